// Round 1
// baseline (1559.040 us; speedup 1.0000x reference)
//
#include <hip/hip_runtime.h>
#include <math.h>

#define NQ 256
#define NK 65536
#define DD 3072
#define TOPK 10
#define BN 64
#define BK 32

typedef unsigned long long u64;
typedef unsigned int u32;

__device__ __forceinline__ float fixv(float x) {
  if (isnan(x)) return 0.0f;
  if (isinf(x)) return x > 0.0f ? 1.0f : -1.0f;
  return x;
}

// Order-preserving map: larger score -> larger key; ties -> smaller idx wins.
__device__ __forceinline__ u64 makekey(float f, int idx) {
  u32 u = __float_as_uint(f);
  u = (u & 0x80000000u) ? ~u : (u | 0x80000000u);
  return ((u64)u << 32) | (u32)(~(u32)idx);
}

// ---------------- kernel 1: per-key inverse L2 norm ----------------
__global__ __launch_bounds__(256) void knorm_kernel(const float* __restrict__ keys,
                                                    float* __restrict__ invnorm) {
  const int wave = threadIdx.x >> 6;
  const int lane = threadIdx.x & 63;
  const int key = (blockIdx.x << 2) + wave;
  const float4* kp = (const float4*)(keys + (size_t)key * DD);
  float s = 0.0f;
#pragma unroll
  for (int c = 0; c < DD / 4 / 64; ++c) {   // 12 iters
    float4 v = kp[lane + c * 64];
    s += v.x * v.x + v.y * v.y + v.z * v.z + v.w * v.w;
  }
#pragma unroll
  for (int off = 32; off > 0; off >>= 1) s += __shfl_xor(s, off);
  if (lane == 0) invnorm[key] = 1.0f / fmaxf(sqrtf(s), 1e-12f);
}

// ---------------- kernel 2: nan_to_num + normalize queries ----------------
__global__ __launch_bounds__(256) void qnorm_kernel(const float* __restrict__ query,
                                                    float* __restrict__ qn) {
  const int b = blockIdx.x;
  const int t = threadIdx.x;
  const float4* qp = (const float4*)(query + (size_t)b * DD);
  float4* op = (float4*)(qn + (size_t)b * DD);
  float4 v[3];
  float s = 0.0f;
#pragma unroll
  for (int i = 0; i < 3; ++i) {   // 3*256*4 = 3072
    float4 x = qp[t + i * 256];
    x.x = fixv(x.x); x.y = fixv(x.y); x.z = fixv(x.z); x.w = fixv(x.w);
    v[i] = x;
    s += x.x * x.x + x.y * x.y + x.z * x.z + x.w * x.w;
  }
#pragma unroll
  for (int off = 32; off > 0; off >>= 1) s += __shfl_xor(s, off);
  __shared__ float red[4];
  if ((t & 63) == 0) red[t >> 6] = s;
  __syncthreads();
  float tot = red[0] + red[1] + red[2] + red[3];
  float inv = 1.0f / fmaxf(sqrtf(tot), 1e-12f);
#pragma unroll
  for (int i = 0; i < 3; ++i) {
    float4 x = v[i];
    x.x *= inv; x.y *= inv; x.z *= inv; x.w *= inv;
    op[t + i * 256] = x;
  }
}

// ---------------- kernel 3: fp32 score GEMM ----------------
// Block tile: all 256 queries x 64 keys -> keys read from HBM exactly once.
// Transposed LDS tiles (At[k][q], Bt[k][n]) so fragment reads are ds_read_b128.
// Row stride padded +4 floats: keeps 16B alignment, spreads write banks.
__global__ __launch_bounds__(256, 3) void gemm_kernel(const float* __restrict__ qn,
                                                      const float* __restrict__ keys,
                                                      const float* __restrict__ invnorm,
                                                      float* __restrict__ scores) {
  __shared__ float At[BK][NQ + 4];   // 32 x 260 = 33.3 KB
  __shared__ float Bt[BK][BN + 4];   // 32 x 68  =  8.7 KB
  const int t = threadIdx.x;
  const int n0 = blockIdx.x * BN;
  const int tx = t & 7;        // key dir   (8)
  const int ty = t >> 3;       // query dir (32)
  const int lr = t >> 3;       // loader row 0..31
  const int lc = (t & 7) * 4;  // loader col {0,4,...,28}

  float acc[8][8];
#pragma unroll
  for (int i = 0; i < 8; ++i)
#pragma unroll
    for (int j = 0; j < 8; ++j) acc[i][j] = 0.0f;

  for (int k0 = 0; k0 < DD; k0 += BK) {
    // stage A (queries): 256 rows x 32 cols
#pragma unroll
    for (int p = 0; p < 8; ++p) {
      int q = lr + p * 32;
      float4 v = *(const float4*)(qn + (size_t)q * DD + k0 + lc);
      At[lc + 0][q] = v.x; At[lc + 1][q] = v.y;
      At[lc + 2][q] = v.z; At[lc + 3][q] = v.w;
    }
    // stage B (keys): 64 rows x 32 cols
#pragma unroll
    for (int p = 0; p < 2; ++p) {
      int n = lr + p * 32;
      float4 v = *(const float4*)(keys + (size_t)(n0 + n) * DD + k0 + lc);
      Bt[lc + 0][n] = v.x; Bt[lc + 1][n] = v.y;
      Bt[lc + 2][n] = v.z; Bt[lc + 3][n] = v.w;
    }
    __syncthreads();

#pragma unroll 4
    for (int kk = 0; kk < BK; ++kk) {
      float a[8], b[8];
      *(float4*)&a[0] = *(const float4*)&At[kk][ty * 8];
      *(float4*)&a[4] = *(const float4*)&At[kk][ty * 8 + 4];
      *(float4*)&b[0] = *(const float4*)&Bt[kk][tx * 8];
      *(float4*)&b[4] = *(const float4*)&Bt[kk][tx * 8 + 4];
#pragma unroll
      for (int i = 0; i < 8; ++i)
#pragma unroll
        for (int j = 0; j < 8; ++j) acc[i][j] += a[i] * b[j];
    }
    __syncthreads();
  }

  // epilogue: scale by key inverse norm, store
  float inv[8];
#pragma unroll
  for (int j = 0; j < 8; ++j) inv[j] = invnorm[n0 + tx * 8 + j];
#pragma unroll
  for (int i = 0; i < 8; ++i) {
    int q = ty * 8 + i;
    float o[8];
#pragma unroll
    for (int j = 0; j < 8; ++j) o[j] = acc[i][j] * inv[j];
    float* dst = scores + (size_t)q * NK + n0 + tx * 8;
    *(float4*)&dst[0] = *(float4*)&o[0];
    *(float4*)&dst[4] = *(float4*)&o[4];
  }
}

// ---------------- kernel 4: per-query top-10 + gather ----------------
__global__ __launch_bounds__(256) void topk_kernel(const float* __restrict__ scores,
                                                   const float* __restrict__ keys,
                                                   float* __restrict__ out_emb,
                                                   float* __restrict__ out_idx) {
  const int b = blockIdx.x;
  const int t = threadIdx.x;
  const float* row = scores + (size_t)b * NK;

  // per-thread running top-10 over its 256 strided elements
  u64 cand[TOPK];
#pragma unroll
  for (int i = 0; i < TOPK; ++i) {
    int n = t + i * 256;
    cand[i] = makekey(row[n], n);
  }
  u64 mn = cand[0]; int mnpos = 0;
#pragma unroll
  for (int i = 1; i < TOPK; ++i)
    if (cand[i] < mn) { mn = cand[i]; mnpos = i; }

  for (int i = TOPK; i < 256; ++i) {
    int n = t + i * 256;
    u64 kk = makekey(row[n], n);
    if (kk > mn) {
      cand[mnpos] = kk;
      mn = cand[0]; mnpos = 0;
#pragma unroll
      for (int j = 1; j < TOPK; ++j)
        if (cand[j] < mn) { mn = cand[j]; mnpos = j; }
    }
  }

  // block-wide: 10 rounds of tree-argmax over 256 per-thread bests
  __shared__ u64 sval[256];
  __shared__ u64 results[TOPK];
  for (int r = 0; r < TOPK; ++r) {
    u64 best = 0;
#pragma unroll
    for (int i = 0; i < TOPK; ++i) best = cand[i] > best ? cand[i] : best;
    sval[t] = best;
    __syncthreads();
    for (int s = 128; s >= 1; s >>= 1) {
      if (t < s) { u64 o = sval[t + s]; if (o > sval[t]) sval[t] = o; }
      __syncthreads();
    }
    u64 win = sval[0];
    // unique owner (idx embedded in key) removes it from its list
#pragma unroll
    for (int i = 0; i < TOPK; ++i)
      if (cand[i] == win) cand[i] = 0;
    if (t == 0) results[r] = win;
    __syncthreads();
  }

  // gather raw key rows + write indices (as float; whole out buffer is f32)
  for (int r = 0; r < TOPK; ++r) {
    u64 win = results[r];
    int idx = (int)(~(u32)win);
    if (t == 0) out_idx[b * TOPK + r] = (float)idx;
    const float4* src = (const float4*)(keys + (size_t)idx * DD);
    float4* dst = (float4*)(out_emb + ((size_t)b * TOPK + r) * DD);
#pragma unroll
    for (int c = 0; c < 3; ++c) dst[t + c * 256] = src[t + c * 256];
  }
}

extern "C" void kernel_launch(void* const* d_in, const int* in_sizes, int n_in,
                              void* d_out, int out_size, void* d_ws, size_t ws_size,
                              hipStream_t stream) {
  const float* query = (const float*)d_in[0];
  const float* keys  = (const float*)d_in[1];
  // k is fixed at 10 by setup_inputs(); hard-coded as TOPK.

  float* ws = (float*)d_ws;
  float* invnorm = ws;                                   // NK floats
  float* qn      = ws + NK;                              // NQ*DD floats
  float* scores  = ws + NK + (size_t)NQ * DD;            // NQ*NK floats (64 MB)

  float* out_emb = (float*)d_out;                        // NQ*TOPK*DD
  float* out_idx = (float*)d_out + (size_t)NQ * TOPK * DD;

  knorm_kernel<<<NK / 4, 256, 0, stream>>>(keys, invnorm);
  qnorm_kernel<<<NQ, 256, 0, stream>>>(query, qn);
  gemm_kernel<<<NK / BN, 256, 0, stream>>>(qn, keys, invnorm, scores);
  topk_kernel<<<NQ, 256, 0, stream>>>(scores, keys, out_emb, out_idx);
}

// Round 3
// 323.922 us; speedup vs baseline: 4.8130x; 4.8130x over previous
//
#include <hip/hip_runtime.h>
#include <math.h>

#define NQ 256
#define NK 65536
#define DD 3072
#define TOPK 10
#define BN 64
#define BK 64
#define KTILES (DD / BK)              // 48
#define ATILE_BYTES (256 * BK * 2)    // 32768 B per k-tile bf16 image

typedef unsigned long long u64;
typedef unsigned int u32;
typedef unsigned short u16;

typedef __attribute__((ext_vector_type(8))) short short8;   // bf16x8 MFMA frag
typedef __attribute__((ext_vector_type(4))) float f32x4;
typedef __attribute__((ext_vector_type(4))) unsigned short us4;

#define GLDS(src, dst)                                                        \
  __builtin_amdgcn_global_load_lds(                                           \
      (const __attribute__((address_space(1))) void*)(src),                   \
      (__attribute__((address_space(3))) void*)(dst), 16, 0, 0)

__device__ __forceinline__ float fixv(float x) {
  if (isnan(x)) return 0.0f;
  if (isinf(x)) return x > 0.0f ? 1.0f : -1.0f;
  return x;
}

// RNE float -> bf16 bits
__device__ __forceinline__ u16 f2bf(float x) {
  u32 u = __float_as_uint(x);
  u32 r = (u + 0x7fffu + ((u >> 16) & 1u)) >> 16;
  return (u16)r;
}

// Order-preserving map: larger score -> larger key; ties -> smaller idx wins.
__device__ __forceinline__ u64 makekey(float f, int idx) {
  u32 u = __float_as_uint(f);
  u = (u & 0x80000000u) ? ~u : (u | 0x80000000u);
  return ((u64)u << 32) | (u32)(~(u32)idx);
}

// ---------- kernel 1: nan_to_num + normalize queries ----------
// Outputs: qn fp32 (rescore) + pre-swizzled bf16 A-tile image (GEMM staging)
__global__ __launch_bounds__(256) void qnorm_kernel(const float* __restrict__ query,
                                                    float* __restrict__ qn,
                                                    u16* __restrict__ apre) {
  const int m = blockIdx.x;
  const int t = threadIdx.x;
  const float4* qp = (const float4*)(query + (size_t)m * DD);
  float4 v[3];
  float s = 0.0f;
#pragma unroll
  for (int i = 0; i < 3; ++i) {
    float4 x = qp[t + i * 256];
    x.x = fixv(x.x); x.y = fixv(x.y); x.z = fixv(x.z); x.w = fixv(x.w);
    v[i] = x;
    s += x.x * x.x + x.y * x.y + x.z * x.z + x.w * x.w;
  }
#pragma unroll
  for (int off = 32; off > 0; off >>= 1) s += __shfl_xor(s, off);
  __shared__ float red[4];
  if ((t & 63) == 0) red[t >> 6] = s;
  __syncthreads();
  float inv = 1.0f / fmaxf(sqrtf(red[0] + red[1] + red[2] + red[3]), 1e-12f);
#pragma unroll
  for (int i = 0; i < 3; ++i) {
    float4 x = v[i];
    x.x *= inv; x.y *= inv; x.z *= inv; x.w *= inv;
    ((float4*)(qn + (size_t)m * DD))[t + i * 256] = x;
    // pre-swizzled bf16 image: tile kt, row m (128 B), byte ^= (m&7)<<4
    int k0 = (t + i * 256) * 4;
    int kt = k0 >> 6;
    int kk = k0 & 63;
    u32 off = (u32)kt * ATILE_BYTES + (((u32)(m * 128 + kk * 2)) ^ (((u32)m & 7) << 4));
    us4 b;
    b.x = f2bf(x.x); b.y = f2bf(x.y); b.z = f2bf(x.z); b.w = f2bf(x.w);
    *(us4*)((char*)apre + off) = b;
  }
}

// ---------- kernel 2: bf16 MFMA score GEMM + fused key-norm ----------
// BM=256 (all queries) x BN=64 keys per block -> each key row read once from HBM.
// A: global_load_lds from pre-swizzled image. B: fp32 load -> ssq accum ->
// bf16 convert -> swizzled ds_write. 4 waves, wave tile 64x64, 16x16x32 MFMA.
__global__ __launch_bounds__(256, 3) void gemm_kernel(const u16* __restrict__ apre,
                                                      const float* __restrict__ keys,
                                                      float* __restrict__ invk,
                                                      float* __restrict__ scores) {
  __shared__ __align__(16) u16 As[256 * BK];  // 32 KB swizzled
  __shared__ __align__(16) u16 Bs[BN * BK];   // 8 KB swizzled
  __shared__ float sinv[BN];
  const int t = threadIdx.x;
  const int w = t >> 6, l = t & 63;
  const int n0 = blockIdx.x * BN;

  f32x4 acc[4][4];
#pragma unroll
  for (int mi = 0; mi < 4; ++mi)
#pragma unroll
    for (int ni = 0; ni < 4; ++ni) acc[mi][ni] = (f32x4){0.f, 0.f, 0.f, 0.f};
  float ssq[4] = {0.f, 0.f, 0.f, 0.f};

  const int br = t >> 4;        // 0..15 (row within 16-row group)
  const int bc = (t & 15) * 4;  // fp32 col {0,4,...,60}

  for (int kt = 0; kt < KTILES; ++kt) {
    __syncthreads();  // previous tile's reads complete
    // A tile: 32 KB async DMA from pre-swizzled image
    const char* asrc = (const char*)apre + (size_t)kt * ATILE_BYTES;
#pragma unroll
    for (int i = 0; i < 8; ++i)
      GLDS(asrc + i * 4096 + t * 16, (char*)As + i * 4096 + t * 16);
    // B tile: 64x64 fp32 -> ssq + bf16 -> swizzled LDS
    const int kb = kt * BK;
#pragma unroll
    for (int i = 0; i < 4; ++i) {
      int row = i * 16 + br;
      float4 v = *(const float4*)(keys + (size_t)(n0 + row) * DD + kb + bc);
      ssq[i] += v.x * v.x + v.y * v.y + v.z * v.z + v.w * v.w;
      us4 b;
      b.x = f2bf(v.x); b.y = f2bf(v.y); b.z = f2bf(v.z); b.w = f2bf(v.w);
      u32 off = ((u32)(row * 128 + bc * 2)) ^ (((u32)row & 7) << 4);
      *(us4*)((char*)Bs + off) = b;
    }
    __syncthreads();  // DMA + ds_writes visible
#pragma unroll
    for (int ks = 0; ks < 2; ++ks) {
      short8 a[4], b[4];
#pragma unroll
      for (int mi = 0; mi < 4; ++mi) {
        int row = w * 64 + mi * 16 + (l & 15);
        u32 off = ((u32)(row * 128 + ks * 64 + (l >> 4) * 16)) ^ (((u32)row & 7) << 4);
        a[mi] = *(const short8*)((const char*)As + off);
      }
#pragma unroll
      for (int ni = 0; ni < 4; ++ni) {
        int row = ni * 16 + (l & 15);
        u32 off = ((u32)(row * 128 + ks * 64 + (l >> 4) * 16)) ^ (((u32)row & 7) << 4);
        b[ni] = *(const short8*)((const char*)Bs + off);
      }
#pragma unroll
      for (int mi = 0; mi < 4; ++mi)
#pragma unroll
        for (int ni = 0; ni < 4; ++ni)
          acc[mi][ni] = __builtin_amdgcn_mfma_f32_16x16x32_bf16(a[mi], b[ni], acc[mi][ni], 0, 0, 0);
    }
  }

  // key inverse norms (16 threads per row, consecutive lanes -> shfl groups)
#pragma unroll
  for (int i = 0; i < 4; ++i) {
    float s = ssq[i];
    s += __shfl_xor(s, 1); s += __shfl_xor(s, 2);
    s += __shfl_xor(s, 4); s += __shfl_xor(s, 8);
    ssq[i] = s;
  }
  if ((t & 15) == 0) {
#pragma unroll
    for (int i = 0; i < 4; ++i) {
      int row = i * 16 + br;
      float iv = 1.0f / fmaxf(sqrtf(ssq[i]), 1e-12f);
      sinv[row] = iv;
      invk[n0 + row] = iv;  // unique writer: this block owns these keys
    }
  }
  __syncthreads();

  // epilogue: scale + store. C frag: col=lane&15, row=(lane>>4)*4+r
#pragma unroll
  for (int ni = 0; ni < 4; ++ni) {
    int nl = ni * 16 + (l & 15);
    float iv = sinv[nl];
#pragma unroll
    for (int mi = 0; mi < 4; ++mi) {
      int q = w * 64 + mi * 16 + (l >> 4) * 4;
#pragma unroll
      for (int r = 0; r < 4; ++r)
        scores[(size_t)(q + r) * NK + n0 + nl] = acc[mi][ni][r] * iv;
    }
  }
}

// ---------- kernel 3: per-(query, 1/8-part) bf16 top-16 ----------
// Static-indexed candidate lists (no scratch). Per-wave top-16 -> ws.
__global__ __launch_bounds__(256) void topk_part(const float* __restrict__ scores,
                                                 u64* __restrict__ cand) {
  const int b = blockIdx.x >> 3, p = blockIdx.x & 7;
  const int t = threadIdx.x;
  const int w = t >> 6, l = t & 63;
  const float4* row4 = (const float4*)(scores + (size_t)b * NK) + p * 2048;

  float4 v[8];
#pragma unroll
  for (int i = 0; i < 8; ++i) v[i] = row4[i * 256 + t];

  u64 c16[16];
#pragma unroll
  for (int i = 0; i < 4; ++i) {
    int nb = (p * 2048 + i * 256 + t) * 4;
    c16[i * 4 + 0] = makekey(v[i].x, nb + 0);
    c16[i * 4 + 1] = makekey(v[i].y, nb + 1);
    c16[i * 4 + 2] = makekey(v[i].z, nb + 2);
    c16[i * 4 + 3] = makekey(v[i].w, nb + 3);
  }
  u64 mn = c16[0];
#pragma unroll
  for (int i = 1; i < 16; ++i) mn = c16[i] < mn ? c16[i] : mn;

#pragma unroll
  for (int i = 4; i < 8; ++i) {
    int nb = (p * 2048 + i * 256 + t) * 4;
    float e[4] = {v[i].x, v[i].y, v[i].z, v[i].w};
#pragma unroll
    for (int j = 0; j < 4; ++j) {
      u64 kk = makekey(e[j], nb + j);
      if (kk > mn) {
#pragma unroll
        for (int q = 0; q < 16; ++q)
          if (c16[q] == mn) c16[q] = kk;  // exactly one match (keys unique)
        u64 m2 = c16[0];
#pragma unroll
        for (int q = 1; q < 16; ++q) m2 = c16[q] < m2 ? c16[q] : m2;
        mn = m2;
      }
    }
  }

  // wave-level top-16 (16 rounds of shfl-max, owner clears)
#pragma unroll 1
  for (int r = 0; r < 16; ++r) {
    u64 best = 0;
#pragma unroll
    for (int i = 0; i < 16; ++i) best = c16[i] > best ? c16[i] : best;
    u64 wb = best;
#pragma unroll
    for (int off = 1; off < 64; off <<= 1) {
      u64 o = __shfl_xor(wb, off);
      wb = o > wb ? o : wb;
    }
#pragma unroll
    for (int i = 0; i < 16; ++i)
      if (c16[i] == wb) c16[i] = 0;  // only the true owner matches
    if (l == 0) cand[(((size_t)b * 8 + p) * 4 + w) * 16 + r] = wb;
  }
}

// ---------- kernel 4: merge 512 cands -> top-16 -> exact rescore -> top-10 + gather ----------
__global__ __launch_bounds__(256) void merge_rescore(const u64* __restrict__ cand,
                                                     const float* __restrict__ qn,
                                                     const float* __restrict__ keys,
                                                     const float* __restrict__ invk,
                                                     float* __restrict__ out_emb,
                                                     float* __restrict__ out_idx) {
  const int b = blockIdx.x;
  const int t = threadIdx.x;
  const int w = t >> 6, l = t & 63;
  __shared__ u64 top16[16];
  __shared__ float exact[16];
  __shared__ int ord[TOPK];

  if (w == 0) {  // wave 0 merges 512 candidates -> top-16
    u64 lc[8];
    const u64* cb = cand + (size_t)b * 512;
#pragma unroll
    for (int i = 0; i < 8; ++i) lc[i] = cb[l * 8 + i];
#pragma unroll 1
    for (int r = 0; r < 16; ++r) {
      u64 best = 0;
#pragma unroll
      for (int i = 0; i < 8; ++i) best = lc[i] > best ? lc[i] : best;
      u64 wb = best;
#pragma unroll
      for (int off = 1; off < 64; off <<= 1) {
        u64 o = __shfl_xor(wb, off);
        wb = o > wb ? o : wb;
      }
#pragma unroll
      for (int i = 0; i < 8; ++i)
        if (lc[i] == wb) lc[i] = 0;
      if (l == 0) top16[r] = wb;
    }
  }
  __syncthreads();

  // exact fp32 rescore: 16 threads per candidate
  {
    const int g = t >> 4, c = t & 15;
    const int idx = (int)(~(u32)top16[g]);
    const float iv = invk[idx];
    const float4* kp = (const float4*)(keys + (size_t)idx * DD);
    const float4* qp = (const float4*)(qn + (size_t)b * DD);
    float s = 0.0f;
    for (int j = 0; j < 48; ++j) {
      float4 kv = kp[j * 16 + c];
      float4 qv = qp[j * 16 + c];
      s = fmaf(qv.x, kv.x * iv, s);
      s = fmaf(qv.y, kv.y * iv, s);
      s = fmaf(qv.z, kv.z * iv, s);
      s = fmaf(qv.w, kv.w * iv, s);
    }
    s += __shfl_xor(s, 1); s += __shfl_xor(s, 2);
    s += __shfl_xor(s, 4); s += __shfl_xor(s, 8);
    if (c == 0) exact[g] = s;
  }
  __syncthreads();

  if (w == 0 && l < 16) {  // top-10 of 16 by exact score
    u64 ek = makekey(exact[l], (int)(~(u32)top16[l]));
#pragma unroll 1
    for (int r = 0; r < TOPK; ++r) {
      u64 wb = ek;
#pragma unroll
      for (int off = 1; off < 16; off <<= 1) {
        u64 o = __shfl_xor(wb, off);
        wb = o > wb ? o : wb;
      }
      if (wb == ek) ek = 0;
      if (l == 0) ord[r] = (int)(~(u32)wb);
    }
  }
  __syncthreads();

  // gather raw key rows + indices (as float; flat f32 out buffer)
  for (int r = 0; r < TOPK; ++r) {
    int idx = ord[r];
    if (t == 0) out_idx[b * TOPK + r] = (float)idx;
    const float4* src = (const float4*)(keys + (size_t)idx * DD);
    float4* dst = (float4*)(out_emb + ((size_t)b * TOPK + r) * DD);
#pragma unroll
    for (int c2 = 0; c2 < 3; ++c2) dst[t + c2 * 256] = src[t + c2 * 256];
  }
}

extern "C" void kernel_launch(void* const* d_in, const int* in_sizes, int n_in,
                              void* d_out, int out_size, void* d_ws, size_t ws_size,
                              hipStream_t stream) {
  const float* query = (const float*)d_in[0];
  const float* keys  = (const float*)d_in[1];

  float* ws = (float*)d_ws;
  float* invk   = ws;                                        // NK floats
  float* qn     = ws + NK;                                   // NQ*DD floats
  u16*   apre   = (u16*)(ws + NK + (size_t)NQ * DD);         // 48*256*64 bf16
  float* scores = ws + NK + (size_t)NQ * DD + (size_t)KTILES * 256 * BK / 2;  // NQ*NK
  u64*   cand   = (u64*)(scores + (size_t)NQ * NK);          // 256*8*4*16 u64

  float* out_emb = (float*)d_out;
  float* out_idx = (float*)d_out + (size_t)NQ * TOPK * DD;

  qnorm_kernel<<<NQ, 256, 0, stream>>>(query, qn, apre);
  gemm_kernel<<<NK / BN, 256, 0, stream>>>(apre, keys, invk, scores);
  topk_part<<<NQ * 8, 256, 0, stream>>>(scores, cand);
  merge_rescore<<<NQ, 256, 0, stream>>>(cand, qn, keys, invk, out_emb, out_idx);
}